// Round 5
// baseline (65.904 us; speedup 1.0000x reference)
//
#include <hip/hip_runtime.h>
#include <hip/hip_fp16.h>

// CapsuleLinear, B=32, I=512, L=64, O=128, J=64, 3 routing iterations.
// Algebraic fusion (no priors):  out = W_o @ xc,  wn = (G_o @ xc)/||out||,
// G_o = W_o^T W_o (precomputed, 2 MB in d_ws).
// MFMA on v_mfma_f32_16x16x32_f16:
//  phase A: logits[i][o] = sum_l x[i][l] wn[o][l]   (A,B frags: b128 LDS reads)
//  phase B: xc[o][l]     = sum_i coef[o][i] x[i][l] (A: b128 LDS; B: x^T frags
//           LOADED ONCE from global into registers — r4's per-pass LDS column
//           gather was ~8-way bank-conflicted and dominated the runtime)
// Pass 0 (xbar) reduces the register fragments directly (no MFMA needed).
// 512 blocks = 2/CU (77 KB LDS), one full-chip round.

#define CB 32
#define CI 512
#define CL 64
#define CO 128
#define OPB 8
#define NT 512

typedef _Float16 half8 __attribute__((ext_vector_type(8)));
typedef float f32x4 __attribute__((ext_vector_type(4)));

__global__ __launch_bounds__(256) void caps_gram(const float* __restrict__ wg,
                                                 float* __restrict__ Gw) {
  const int o = blockIdx.x;
  const int t = threadIdx.x;
  __shared__ float wl[64 * 65];
#pragma unroll
  for (int k = 0; k < 16; ++k) {
    int f = t + 256 * k;
    int j = f >> 6, l = f & 63;
    wl[j * 65 + l] = wg[(o << 12) + f];
  }
  __syncthreads();
  const int l1 = t >> 2;
  const int l2b = (t & 3) << 4;
  float acc[16];
#pragma unroll
  for (int m = 0; m < 16; ++m) acc[m] = 0.f;
#pragma unroll 4
  for (int j = 0; j < 64; ++j) {
    float wa = wl[j * 65 + l1];
#pragma unroll
    for (int m = 0; m < 16; ++m) acc[m] += wa * wl[j * 65 + l2b + m];
  }
#pragma unroll
  for (int m = 0; m < 16; ++m) Gw[(o << 12) + (l1 << 6) + l2b + m] = acc[m];
}

__global__ __launch_bounds__(NT, 4) void caps_main(const float* __restrict__ xg,
                                                   const float* __restrict__ wg,
                                                   const float* __restrict__ Gw,
                                                   float* __restrict__ outg) {
  const int b = blockIdx.y;
  const int obase = blockIdx.x * OPB;
  const int t = threadIdx.x;
  const int w = t >> 6;          // wave id
  const int lane = t & 63;
  const int g = lane >> 4;       // 16-lane group
  const int o15 = lane & 15;     // MFMA row/col index
  const int oc = o15 & 7;

  // xs: 32 i-subtiles x 4 l-subtiles, each 16x16 halves row-major = 512 B.
  __shared__ __align__(16) _Float16 xs[CI * CL];        // 65536 B
  __shared__ __align__(16) _Float16 coefT[OPB * CI];    // 8192 B (unit-XOR swz)
  __shared__ __align__(16) _Float16 wn16[OPB * CL];     // 1024 B (unit-XOR swz)
  __shared__ __align__(16) float xc_s[OPB * CL];        // 2048 B
  __shared__ float se_part[OPB * OPB];                  // 256 B
  float* const xcpart = reinterpret_cast<float*>(coefT);  // overlay (barrier-sep)
  char* const xs_b = reinterpret_cast<char*>(xs);
  char* const cf_b = reinterpret_cast<char*>(coefT);
  char* const wn_b = reinterpret_cast<char*>(wn16);
  // total 77312 B -> 2 blocks/CU

  const int kh = w >> 2, nt = w & 3;  // phase-B: K-half, l-subtile

  // ---- x^T B-fragments, loaded ONCE from global into registers ----
  // bfrag[ks].h[j] = x[kh*256 + ks*32 + 8g + j][nt*16 + o15]  (fp32 -> fp16)
  union Frag { _Float16 h[8]; half8 v; };
  Frag bfrag[8];
  {
    const float* xb = xg + b * (CI * CL) + (nt * 16 + o15);
#pragma unroll
    for (int ks = 0; ks < 8; ++ks) {
      const float* xr = xb + (kh * 256 + ks * 32 + 8 * g) * 64;
#pragma unroll
      for (int j = 0; j < 8; ++j) bfrag[ks].h[j] = (_Float16)xr[j * 64];
    }
  }

  // G column (fp32): g_reg[l2] = G[obase+w][l2][lane]  (G symmetric)
  float g_reg[64];
  {
    const float* Gp = Gw + ((obase + w) << 12) + lane;
#pragma unroll
    for (int l2 = 0; l2 < 64; ++l2) g_reg[l2] = Gp[l2 << 6];
  }

  // ---- stage x[b] -> fp16 subtiled LDS (phase-A A-operands only) ----
  {
    const float4* xg4 = reinterpret_cast<const float4*>(xg + b * (CI * CL));
#pragma unroll
    for (int k = 0; k < 8; ++k) {
      int f = t + NT * k;        // 8-half unit id: row i, l-unit lu
      int i = f >> 3, lu = f & 7;
      float4 a = xg4[2 * f];
      float4 c = xg4[2 * f + 1];
      union { _Float16 h[8]; uint4 u; } cv;
      cv.h[0] = (_Float16)a.x; cv.h[1] = (_Float16)a.y;
      cv.h[2] = (_Float16)a.z; cv.h[3] = (_Float16)a.w;
      cv.h[4] = (_Float16)c.x; cv.h[5] = (_Float16)c.y;
      cv.h[6] = (_Float16)c.z; cv.h[7] = (_Float16)c.w;
      int off = ((i >> 4) * 4 + (lu >> 1)) * 512 + (i & 15) * 32 + (lu & 1) * 16;
      *reinterpret_cast<uint4*>(xs_b + off) = cv.u;
    }
  }

  for (int pass = 0; pass < 4; ++pass) {
    if (pass > 0) {
      // ---- phase A: logits via MFMA; exp; coef+se ----
      half8 bw0 = *reinterpret_cast<const half8*>(wn_b + oc * 128 + ((g ^ oc) << 4));
      half8 bw1 = *reinterpret_cast<const half8*>(wn_b + oc * 128 + (((4 + g) ^ oc) << 4));
      float sacc = 0.f;
#pragma unroll
      for (int ti = 0; ti < 4; ++ti) {
        const int itb = (16 * w + 4 * ti) * 512;  // i-subtile (4w+ti) byte base
        half8 a0 = *reinterpret_cast<const half8*>(
            xs_b + itb + ((g >> 1) * 512) + o15 * 32 + ((g & 1) << 4));
        half8 a1 = *reinterpret_cast<const half8*>(
            xs_b + itb + ((2 + (g >> 1)) * 512) + o15 * 32 + ((g & 1) << 4));
        f32x4 d = {0.f, 0.f, 0.f, 0.f};
        d = __builtin_amdgcn_mfma_f32_16x16x32_f16(a0, bw0, d, 0, 0, 0);
        d = __builtin_amdgcn_mfma_f32_16x16x32_f16(a1, bw1, d, 0, 0, 0);
        // |logits| <= ||x_i||*sigma_max(W_o) ~ 2.5: no max-subtraction needed
        float e0 = __expf(d[0]), e1 = __expf(d[1]);
        float e2 = __expf(d[2]), e3 = __expf(d[3]);
        sacc += (e0 + e1) + (e2 + e3);
        if (o15 < 8) {  // valid capsule columns only
          int p = 8 * w + 2 * ti + (g >> 1);          // 8-half unit index (i>>3)
          int base = o15 * 1024 + ((p ^ o15) << 4) + ((g & 1) << 3);
          union { _Float16 h[2]; uint u; } p0, p1;
          p0.h[0] = (_Float16)e0; p0.h[1] = (_Float16)e1;
          p1.h[0] = (_Float16)e2; p1.h[1] = (_Float16)e3;
          *reinterpret_cast<uint*>(cf_b + base) = p0.u;
          *reinterpret_cast<uint*>(cf_b + base + 4) = p1.u;
        }
      }
      sacc += __shfl_xor(sacc, 16, 64);
      sacc += __shfl_xor(sacc, 32, 64);
      if (lane < 8) se_part[w * 8 + lane] = sacc;
      __syncthreads();
    }

    // ---- phase B ----
    if (pass == 0) {
      // xbar partials straight from register fragments: sum over this wave's
      // 64 rows for column nt*16+o15, then reduce across the 4 groups.
      float s = 0.f;
#pragma unroll
      for (int ks = 0; ks < 8; ++ks)
#pragma unroll
        for (int j = 0; j < 8; ++j) s += (float)bfrag[ks].h[j];
      s += __shfl_xor(s, 16, 64);
      s += __shfl_xor(s, 32, 64);
      if (lane < 16) xcpart[kh * 64 + nt * 16 + o15] = s;  // [2][64] overlay
    } else {
      // xc partials via MFMA (A=coef b128, B=x^T register fragments)
      f32x4 d = {0.f, 0.f, 0.f, 0.f};
#pragma unroll
      for (int ks = 0; ks < 8; ++ks) {
        int p = kh * 32 + ks * 4 + g;
        half8 a = *reinterpret_cast<const half8*>(cf_b + oc * 1024 + ((p ^ oc) << 4));
        d = __builtin_amdgcn_mfma_f32_16x16x32_f16(a, bfrag[ks].v, d, 0, 0, 0);
      }
      __syncthreads();  // all coefT reads done before overlay write
      if (lane < 32) {  // D rows 0-7 (valid o) live in lanes 0-31
#pragma unroll
        for (int r = 0; r < 4; ++r)
          xcpart[kh * 512 + (g * 4 + r) * 64 + nt * 16 + o15] = d[r];
      }
    }
    __syncthreads();

    // ---- finalize: xc = partials/denom; wn = (G@xc)/||out|| ----
    {
      float xcv;
      if (pass == 0) {
        xcv = (xcpart[lane] + xcpart[64 + lane]) * (1.0f / 512.0f);
      } else {
        float se = 0.f;
#pragma unroll
        for (int g8 = 0; g8 < 8; ++g8) se += se_part[g8 * 8 + w];
        xcv = (xcpart[w * 64 + lane] + xcpart[512 + w * 64 + lane]) / se;
      }
      xc_s[(w << 6) + lane] = xcv;
      if (pass < 3) {
        const float4* xc4 = reinterpret_cast<const float4*>(&xc_s[w << 6]);
        float u0 = 0.f, u1 = 0.f, u2 = 0.f, u3 = 0.f;
#pragma unroll
        for (int k = 0; k < 16; ++k) {
          float4 xv = xc4[k];
          u0 += g_reg[4 * k + 0] * xv.x;
          u1 += g_reg[4 * k + 1] * xv.y;
          u2 += g_reg[4 * k + 2] * xv.z;
          u3 += g_reg[4 * k + 3] * xv.w;
        }
        float uv = (u0 + u1) + (u2 + u3);
        float sq = uv * xcv;
#pragma unroll
        for (int m = 32; m; m >>= 1) sq += __shfl_xor(sq, m, 64);
        float wnv = uv / fmaxf(sqrtf(fmaxf(sq, 0.f)), 1e-12f);
        union { _Float16 hf; unsigned short us; } wc;
        wc.hf = (_Float16)wnv;
        *reinterpret_cast<unsigned short*>(
            wn_b + w * 128 + (((lane >> 3) ^ w) << 4) + ((lane & 7) << 1)) = wc.us;
      }
    }
    __syncthreads();
  }

  // ---- epilogue: out[b, obase+w, j=lane] = sum_l W[o][j][l] * xc[o][l] ----
  {
    const float* Wp = wg + ((((obase + w) << 6) + lane) << 6);
    float a0 = 0.f, a1 = 0.f, a2 = 0.f, a3 = 0.f;
#pragma unroll
    for (int k = 0; k < 16; ++k) {
      float4 wv = *reinterpret_cast<const float4*>(&Wp[k << 2]);
      float4 xv = *reinterpret_cast<const float4*>(&xc_s[(w << 6) + (k << 2)]);
      a0 += wv.x * xv.x; a1 += wv.y * xv.y;
      a2 += wv.z * xv.z; a3 += wv.w * xv.w;
    }
    outg[((b << 7) + obase + w) * 64 + lane] = (a0 + a1) + (a2 + a3);
  }
}

extern "C" void kernel_launch(void* const* d_in, const int* in_sizes, int n_in,
                              void* d_out, int out_size, void* d_ws, size_t ws_size,
                              hipStream_t stream) {
  const float* x = (const float*)d_in[0];     // (32, 512, 64) fp32
  const float* wgt = (const float*)d_in[1];   // (128, 64, 64) fp32
  float* out = (float*)d_out;                 // (32, 128, 64) fp32
  float* G = (float*)d_ws;                    // 128*64*64 fp32 = 2 MB

  caps_gram<<<dim3(CO), dim3(256), 0, stream>>>(wgt, G);
  caps_main<<<dim3(CO / OPB, CB), dim3(NT), 0, stream>>>(x, wgt, G, out);
}

// Round 6
// 64.792 us; speedup vs baseline: 1.0172x; 1.0172x over previous
//
#include <hip/hip_runtime.h>
#include <hip/hip_fp16.h>

// CapsuleLinear, B=32, I=512, L=64, O=128, J=64, 3 routing iterations.
// Algebraic fusion (no priors):  out = W_o @ xc,  wn = (G_o @ xc)/||out||,
// G_o = W_o^T W_o (precomputed, 2 MB in d_ws).
// MFMA on v_mfma_f32_16x16x32_f16:
//  phase A: logits[i][o] = sum_l x[i][l] wn[o][l]   (A,B frags: b128 LDS reads)
//  phase B: xc[o][l]     = sum_i coef[o][i] x[i][l] (A: b128 LDS; B: x^T frags
//           gathered from LDS ONCE into registers and reused across all passes
//           — r4 re-gathered per pass (4x the 8-way-conflict cost); r5 sourced
//           from global (uncoalesced, 92 MB fetch, worse). Hoist only.)
// Pass 0 (xbar) reduces the register fragments directly (no MFMA needed).
// 512 blocks = 2/CU (77 KB LDS), one full-chip round.

#define CB 32
#define CI 512
#define CL 64
#define CO 128
#define OPB 8
#define NT 512

typedef _Float16 half8 __attribute__((ext_vector_type(8)));
typedef float f32x4 __attribute__((ext_vector_type(4)));

__global__ __launch_bounds__(256) void caps_gram(const float* __restrict__ wg,
                                                 float* __restrict__ Gw) {
  const int o = blockIdx.x;
  const int t = threadIdx.x;
  __shared__ float wl[64 * 65];
#pragma unroll
  for (int k = 0; k < 16; ++k) {
    int f = t + 256 * k;
    int j = f >> 6, l = f & 63;
    wl[j * 65 + l] = wg[(o << 12) + f];
  }
  __syncthreads();
  const int l1 = t >> 2;
  const int l2b = (t & 3) << 4;
  float acc[16];
#pragma unroll
  for (int m = 0; m < 16; ++m) acc[m] = 0.f;
#pragma unroll 4
  for (int j = 0; j < 64; ++j) {
    float wa = wl[j * 65 + l1];
#pragma unroll
    for (int m = 0; m < 16; ++m) acc[m] += wa * wl[j * 65 + l2b + m];
  }
#pragma unroll
  for (int m = 0; m < 16; ++m) Gw[(o << 12) + (l1 << 6) + l2b + m] = acc[m];
}

__global__ __launch_bounds__(NT, 4) void caps_main(const float* __restrict__ xg,
                                                   const float* __restrict__ wg,
                                                   const float* __restrict__ Gw,
                                                   float* __restrict__ outg) {
  const int b = blockIdx.y;
  const int obase = blockIdx.x * OPB;
  const int t = threadIdx.x;
  const int w = t >> 6;          // wave id
  const int lane = t & 63;
  const int g = lane >> 4;       // 16-lane group
  const int o15 = lane & 15;     // MFMA row/col index
  const int oc = o15 & 7;

  // xs: 32 i-subtiles x 4 l-subtiles, each 16x16 halves row-major = 512 B.
  __shared__ __align__(16) _Float16 xs[CI * CL];        // 65536 B
  __shared__ __align__(16) _Float16 coefT[OPB * CI];    // 8192 B (unit-XOR swz)
  __shared__ __align__(16) _Float16 wn16[OPB * CL];     // 1024 B (unit-XOR swz)
  __shared__ __align__(16) float xc_s[OPB * CL];        // 2048 B
  __shared__ float se_part[OPB * OPB];                  // 256 B
  float* const xcpart = reinterpret_cast<float*>(coefT);  // overlay (barrier-sep)
  char* const xs_b = reinterpret_cast<char*>(xs);
  char* const cf_b = reinterpret_cast<char*>(coefT);
  char* const wn_b = reinterpret_cast<char*>(wn16);
  // total 77056 B -> 2 blocks/CU

  const int kh = w >> 2, nt = w & 3;  // phase-B: K-half, l-subtile

  // G column (fp32): g_reg[l2] = G[obase+w][l2][lane]  (G symmetric)
  float g_reg[64];
  {
    const float* Gp = Gw + ((obase + w) << 12) + lane;
#pragma unroll
    for (int l2 = 0; l2 < 64; ++l2) g_reg[l2] = Gp[l2 << 6];
  }

  // ---- stage x[b] -> fp16 subtiled LDS; coalesced float4 global reads ----
  {
    const float4* xg4 = reinterpret_cast<const float4*>(xg + b * (CI * CL));
#pragma unroll
    for (int k = 0; k < 8; ++k) {
      int f = t + NT * k;        // 8-half unit id: row i, l-unit lu
      int i = f >> 3, lu = f & 7;
      float4 a = xg4[2 * f];
      float4 c = xg4[2 * f + 1];
      union { _Float16 h[8]; uint4 u; } cv;
      cv.h[0] = (_Float16)a.x; cv.h[1] = (_Float16)a.y;
      cv.h[2] = (_Float16)a.z; cv.h[3] = (_Float16)a.w;
      cv.h[4] = (_Float16)c.x; cv.h[5] = (_Float16)c.y;
      cv.h[6] = (_Float16)c.z; cv.h[7] = (_Float16)c.w;
      int off = ((i >> 4) * 4 + (lu >> 1)) * 512 + (i & 15) * 32 + (lu & 1) * 16;
      *reinterpret_cast<uint4*>(xs_b + off) = cv.u;
    }
  }
  __syncthreads();

  // ---- x^T B-fragments: gathered from LDS ONCE, reused across all passes ----
  // bfrag[ks].h[j] = x[kh*256 + ks*32 + 8g + j][nt*16 + o15]
  union Frag { _Float16 h[8]; half8 v; };
  Frag bfrag[8];
  {
    const _Float16* xrd = reinterpret_cast<const _Float16*>(
        xs_b + ((kh * 16 + (g >> 1)) * 4 + nt) * 512 + ((lane & 16) << 4) +
        (o15 << 1));  // (g&1)*256 == (lane&16)<<4
#pragma unroll
    for (int ks = 0; ks < 8; ++ks) {
      const _Float16* xk = xrd + ks * 2048;  // +ks*4096 B
#pragma unroll
      for (int j = 0; j < 8; ++j) bfrag[ks].h[j] = xk[j * 16];  // 32 B row pitch
    }
  }

  for (int pass = 0; pass < 4; ++pass) {
    if (pass > 0) {
      // ---- phase A: logits via MFMA; exp; coef+se ----
      half8 bw0 = *reinterpret_cast<const half8*>(wn_b + oc * 128 + ((g ^ oc) << 4));
      half8 bw1 = *reinterpret_cast<const half8*>(wn_b + oc * 128 + (((4 + g) ^ oc) << 4));
      float sacc = 0.f;
#pragma unroll
      for (int ti = 0; ti < 4; ++ti) {
        const int itb = (16 * w + 4 * ti) * 512;  // i-subtile (4w+ti) byte base
        half8 a0 = *reinterpret_cast<const half8*>(
            xs_b + itb + ((g >> 1) * 512) + o15 * 32 + ((g & 1) << 4));
        half8 a1 = *reinterpret_cast<const half8*>(
            xs_b + itb + ((2 + (g >> 1)) * 512) + o15 * 32 + ((g & 1) << 4));
        f32x4 d = {0.f, 0.f, 0.f, 0.f};
        d = __builtin_amdgcn_mfma_f32_16x16x32_f16(a0, bw0, d, 0, 0, 0);
        d = __builtin_amdgcn_mfma_f32_16x16x32_f16(a1, bw1, d, 0, 0, 0);
        // |logits| <= ||x_i||*sigma_max(W_o) ~ 2.5: no max-subtraction needed
        float e0 = __expf(d[0]), e1 = __expf(d[1]);
        float e2 = __expf(d[2]), e3 = __expf(d[3]);
        sacc += (e0 + e1) + (e2 + e3);
        if (o15 < 8) {  // valid capsule columns only
          int p = 8 * w + 2 * ti + (g >> 1);          // 8-half unit index (i>>3)
          int base = o15 * 1024 + ((p ^ o15) << 4) + ((g & 1) << 3);
          union { _Float16 h[2]; uint u; } p0, p1;
          p0.h[0] = (_Float16)e0; p0.h[1] = (_Float16)e1;
          p1.h[0] = (_Float16)e2; p1.h[1] = (_Float16)e3;
          *reinterpret_cast<uint*>(cf_b + base) = p0.u;
          *reinterpret_cast<uint*>(cf_b + base + 4) = p1.u;
        }
      }
      sacc += __shfl_xor(sacc, 16, 64);
      sacc += __shfl_xor(sacc, 32, 64);
      if (lane < 8) se_part[w * 8 + lane] = sacc;
      __syncthreads();
    }

    // ---- phase B ----
    if (pass == 0) {
      // xbar partials straight from register fragments: this wave covers
      // rows kh*256..kh*256+255 for column nt*16+o15 (groups g partition rows)
      float s = 0.f;
#pragma unroll
      for (int ks = 0; ks < 8; ++ks)
#pragma unroll
        for (int j = 0; j < 8; ++j) s += (float)bfrag[ks].h[j];
      s += __shfl_xor(s, 16, 64);
      s += __shfl_xor(s, 32, 64);
      if (lane < 16) xcpart[kh * 64 + nt * 16 + o15] = s;  // [2][64] overlay
    } else {
      // xc partials via MFMA (A=coef b128, B=x^T register fragments)
      f32x4 d = {0.f, 0.f, 0.f, 0.f};
#pragma unroll
      for (int ks = 0; ks < 8; ++ks) {
        int p = kh * 32 + ks * 4 + g;
        half8 a = *reinterpret_cast<const half8*>(cf_b + oc * 1024 + ((p ^ oc) << 4));
        d = __builtin_amdgcn_mfma_f32_16x16x32_f16(a, bfrag[ks].v, d, 0, 0, 0);
      }
      __syncthreads();  // all coefT reads done before overlay write
      if (lane < 32) {  // D rows 0-7 (valid o) live in lanes 0-31
#pragma unroll
        for (int r = 0; r < 4; ++r)
          xcpart[kh * 512 + (g * 4 + r) * 64 + nt * 16 + o15] = d[r];
      }
    }
    __syncthreads();

    // ---- finalize: xc = partials/denom; wn = (G@xc)/||out|| ----
    {
      float xcv;
      if (pass == 0) {
        xcv = (xcpart[lane] + xcpart[64 + lane]) * (1.0f / 512.0f);
      } else {
        float se = 0.f;
#pragma unroll
        for (int g8 = 0; g8 < 8; ++g8) se += se_part[g8 * 8 + w];
        xcv = (xcpart[w * 64 + lane] + xcpart[512 + w * 64 + lane]) / se;
      }
      xc_s[(w << 6) + lane] = xcv;
      if (pass < 3) {
        const float4* xc4 = reinterpret_cast<const float4*>(&xc_s[w << 6]);
        float u0 = 0.f, u1 = 0.f, u2 = 0.f, u3 = 0.f;
#pragma unroll
        for (int k = 0; k < 16; ++k) {
          float4 xv = xc4[k];
          u0 += g_reg[4 * k + 0] * xv.x;
          u1 += g_reg[4 * k + 1] * xv.y;
          u2 += g_reg[4 * k + 2] * xv.z;
          u3 += g_reg[4 * k + 3] * xv.w;
        }
        float uv = (u0 + u1) + (u2 + u3);
        float sq = uv * xcv;
#pragma unroll
        for (int m = 32; m; m >>= 1) sq += __shfl_xor(sq, m, 64);
        float wnv = uv / fmaxf(sqrtf(fmaxf(sq, 0.f)), 1e-12f);
        union { _Float16 hf; unsigned short us; } wc;
        wc.hf = (_Float16)wnv;
        *reinterpret_cast<unsigned short*>(
            wn_b + w * 128 + (((lane >> 3) ^ w) << 4) + ((lane & 7) << 1)) = wc.us;
      }
    }
    __syncthreads();
  }

  // ---- epilogue: out[b, obase+w, j=lane] = sum_l W[o][j][l] * xc[o][l] ----
  {
    const float* Wp = wg + ((((obase + w) << 6) + lane) << 6);
    float a0 = 0.f, a1 = 0.f, a2 = 0.f, a3 = 0.f;
#pragma unroll
    for (int k = 0; k < 16; ++k) {
      float4 wv = *reinterpret_cast<const float4*>(&Wp[k << 2]);
      float4 xv = *reinterpret_cast<const float4*>(&xc_s[(w << 6) + (k << 2)]);
      a0 += wv.x * xv.x; a1 += wv.y * xv.y;
      a2 += wv.z * xv.z; a3 += wv.w * xv.w;
    }
    outg[((b << 7) + obase + w) * 64 + lane] = (a0 + a1) + (a2 + a3);
  }
}

extern "C" void kernel_launch(void* const* d_in, const int* in_sizes, int n_in,
                              void* d_out, int out_size, void* d_ws, size_t ws_size,
                              hipStream_t stream) {
  const float* x = (const float*)d_in[0];     // (32, 512, 64) fp32
  const float* wgt = (const float*)d_in[1];   // (128, 64, 64) fp32
  float* out = (float*)d_out;                 // (32, 128, 64) fp32
  float* G = (float*)d_ws;                    // 128*64*64 fp32 = 2 MB

  caps_gram<<<dim3(CO), dim3(256), 0, stream>>>(wgt, G);
  caps_main<<<dim3(CO / OPB, CB), dim3(NT), 0, stream>>>(x, wgt, G, out);
}

// Round 7
// 63.556 us; speedup vs baseline: 1.0369x; 1.0194x over previous
//
#include <hip/hip_runtime.h>
#include <hip/hip_fp16.h>

// CapsuleLinear, B=32, I=512, L=64, O=128, J=64, 3 routing iterations.
// Algebraic fusion (no priors):  out = W_o @ xc,  wn = (G_o @ xc)/||out||,
// G_o = W_o^T W_o (precomputed fp16-packed, 1 MB in d_ws).
// MFMA on v_mfma_f32_16x16x32_f16:
//  phase A: logits[i][o] = sum_l x[i][l] wn[o][l]   (A,B frags: b128 LDS reads)
//  phase B: xc[o][l]     = sum_i coef[o][i] x[i][l] (A: b128 LDS; B: x^T frags
//           gathered from LDS once into registers, reused across passes)
// r6 post-mortem: WRITE_SIZE 58 MB = scratch spills (g_reg 64 + bfrag 32 VGPRs
// vs compiler's self-chosen 64-VGPR budget). Fixes here:
//  - amdgpu_waves_per_eu(4,4): pin occupancy, unlock the full 128-VGPR budget
//  - G as packed fp16 pairs (32 VGPRs, halved)
//  - dedicated xcpart buffer: 3 barriers/pass instead of 4 (LDS 81,152 B)

#define CB 32
#define CI 512
#define CL 64
#define CO 128
#define OPB 8
#define NT 512

typedef _Float16 half8 __attribute__((ext_vector_type(8)));
typedef float f32x4 __attribute__((ext_vector_type(4)));

// Gh2[o][l2p][l] = (G[o][2*l2p][l], G[o][2*l2p+1][l]) as __half2; 128*32*64.
__global__ __launch_bounds__(256) void caps_gram(const float* __restrict__ wg,
                                                 __half2* __restrict__ Gh2) {
  const int o = blockIdx.x;
  const int t = threadIdx.x;
  __shared__ float wl[64 * 65];  // W[o] padded
  __shared__ float gl[64 * 65];  // G[o] padded
#pragma unroll
  for (int k = 0; k < 16; ++k) {
    int f = t + 256 * k;
    int j = f >> 6, l = f & 63;
    wl[j * 65 + l] = wg[(o << 12) + f];
  }
  __syncthreads();
  const int l1 = t >> 2;
  const int l2b = (t & 3) << 4;
  float acc[16];
#pragma unroll
  for (int m = 0; m < 16; ++m) acc[m] = 0.f;
#pragma unroll 4
  for (int j = 0; j < 64; ++j) {
    float wa = wl[j * 65 + l1];
#pragma unroll
    for (int m = 0; m < 16; ++m) acc[m] += wa * wl[j * 65 + l2b + m];
  }
#pragma unroll
  for (int m = 0; m < 16; ++m) gl[l1 * 65 + l2b + m] = acc[m];
  __syncthreads();
#pragma unroll
  for (int k = 0; k < 8; ++k) {
    int e = t + 256 * k;          // 0..2047
    int l2p = e >> 6, l = e & 63;
    Gh2[(o << 11) + e] =
        __floats2half2_rn(gl[(2 * l2p) * 65 + l], gl[(2 * l2p + 1) * 65 + l]);
  }
}

__global__ __launch_bounds__(NT)
__attribute__((amdgpu_waves_per_eu(4, 4)))
void caps_main(const float* __restrict__ xg,
               const float* __restrict__ wg,
               const __half2* __restrict__ Gh2,
               float* __restrict__ outg) {
  const int b = blockIdx.y;
  const int obase = blockIdx.x * OPB;
  const int t = threadIdx.x;
  const int w = t >> 6;          // wave id
  const int lane = t & 63;
  const int g = lane >> 4;       // 16-lane group
  const int o15 = lane & 15;     // MFMA row/col index
  const int oc = o15 & 7;

  // xs: 32 i-subtiles x 4 l-subtiles, each 16x16 halves row-major = 512 B.
  __shared__ __align__(16) _Float16 xs[CI * CL];        // 65536 B
  __shared__ __align__(16) _Float16 coefT[OPB * CI];    // 8192 B (unit-XOR swz)
  __shared__ __align__(16) _Float16 wn16[OPB * CL];     // 1024 B (unit-XOR swz)
  __shared__ __align__(16) float xc_s[OPB * CL];        // 2048 B
  __shared__ __align__(16) float xcpart[2 * OPB * CL];  // 4096 B (dedicated)
  __shared__ float se_part[OPB * OPB];                  // 256 B
  char* const xs_b = reinterpret_cast<char*>(xs);
  char* const cf_b = reinterpret_cast<char*>(coefT);
  char* const wn_b = reinterpret_cast<char*>(wn16);
  // total 81152 B -> 2 blocks/CU (<= 81920)

  const int kh = w >> 2, nt = w & 3;  // phase-B: K-half, l-subtile

  // G rows (fp16 pairs): gh[p] = (G[o][2p][lane], G[o][2p+1][lane])
  __half2 gh[32];
  {
    const __half2* Gp = Gh2 + ((obase + w) << 11) + lane;
#pragma unroll
    for (int p = 0; p < 32; ++p) gh[p] = Gp[p << 6];
  }

  // ---- stage x[b] -> fp16 subtiled LDS; coalesced float4 global reads ----
  {
    const float4* xg4 = reinterpret_cast<const float4*>(xg + b * (CI * CL));
#pragma unroll
    for (int k = 0; k < 8; ++k) {
      int f = t + NT * k;        // 8-half unit id: row i, l-unit lu
      int i = f >> 3, lu = f & 7;
      float4 a = xg4[2 * f];
      float4 c = xg4[2 * f + 1];
      union { _Float16 h[8]; uint4 u; } cv;
      cv.h[0] = (_Float16)a.x; cv.h[1] = (_Float16)a.y;
      cv.h[2] = (_Float16)a.z; cv.h[3] = (_Float16)a.w;
      cv.h[4] = (_Float16)c.x; cv.h[5] = (_Float16)c.y;
      cv.h[6] = (_Float16)c.z; cv.h[7] = (_Float16)c.w;
      int off = ((i >> 4) * 4 + (lu >> 1)) * 512 + (i & 15) * 32 + (lu & 1) * 16;
      *reinterpret_cast<uint4*>(xs_b + off) = cv.u;
    }
  }
  __syncthreads();

  // ---- x^T B-fragments: gathered from LDS ONCE, reused across all passes ----
  // bfrag[ks].h[j] = x[kh*256 + ks*32 + 8g + j][nt*16 + o15]
  union Frag { _Float16 h[8]; half8 v; };
  Frag bfrag[8];
  {
    const _Float16* xrd = reinterpret_cast<const _Float16*>(
        xs_b + ((kh * 16 + (g >> 1)) * 4 + nt) * 512 + ((lane & 16) << 4) +
        (o15 << 1));  // (g&1)*256 == (lane&16)<<4
#pragma unroll
    for (int ks = 0; ks < 8; ++ks) {
      const _Float16* xk = xrd + ks * 2048;  // +ks*4096 B
#pragma unroll
      for (int j = 0; j < 8; ++j) bfrag[ks].h[j] = xk[j * 16];  // 32 B row pitch
    }
  }

  for (int pass = 0; pass < 4; ++pass) {
    if (pass > 0) {
      // ---- phase A: logits via MFMA; exp; coef+se ----
      half8 bw0 = *reinterpret_cast<const half8*>(wn_b + oc * 128 + ((g ^ oc) << 4));
      half8 bw1 = *reinterpret_cast<const half8*>(wn_b + oc * 128 + (((4 + g) ^ oc) << 4));
      float sacc = 0.f;
#pragma unroll
      for (int ti = 0; ti < 4; ++ti) {
        const int itb = (16 * w + 4 * ti) * 512;  // i-subtile (4w+ti) byte base
        half8 a0 = *reinterpret_cast<const half8*>(
            xs_b + itb + ((g >> 1) * 512) + o15 * 32 + ((g & 1) << 4));
        half8 a1 = *reinterpret_cast<const half8*>(
            xs_b + itb + ((2 + (g >> 1)) * 512) + o15 * 32 + ((g & 1) << 4));
        f32x4 d = {0.f, 0.f, 0.f, 0.f};
        d = __builtin_amdgcn_mfma_f32_16x16x32_f16(a0, bw0, d, 0, 0, 0);
        d = __builtin_amdgcn_mfma_f32_16x16x32_f16(a1, bw1, d, 0, 0, 0);
        // |logits| <= ||x_i||*sigma_max(W_o) ~ 2.5: no max-subtraction needed
        float e0 = __expf(d[0]), e1 = __expf(d[1]);
        float e2 = __expf(d[2]), e3 = __expf(d[3]);
        sacc += (e0 + e1) + (e2 + e3);
        if (o15 < 8) {  // valid capsule columns only
          int p = 8 * w + 2 * ti + (g >> 1);          // 8-half unit index (i>>3)
          int base = o15 * 1024 + ((p ^ o15) << 4) + ((g & 1) << 3);
          union { _Float16 h[2]; uint u; } p0, p1;
          p0.h[0] = (_Float16)e0; p0.h[1] = (_Float16)e1;
          p1.h[0] = (_Float16)e2; p1.h[1] = (_Float16)e3;
          *reinterpret_cast<uint*>(cf_b + base) = p0.u;
          *reinterpret_cast<uint*>(cf_b + base + 4) = p1.u;
        }
      }
      sacc += __shfl_xor(sacc, 16, 64);
      sacc += __shfl_xor(sacc, 32, 64);
      if (lane < 8) se_part[w * 8 + lane] = sacc;
      __syncthreads();
    }

    // ---- phase B ----
    if (pass == 0) {
      // xbar partials straight from register fragments
      float s = 0.f;
#pragma unroll
      for (int ks = 0; ks < 8; ++ks)
#pragma unroll
        for (int j = 0; j < 8; ++j) s += (float)bfrag[ks].h[j];
      s += __shfl_xor(s, 16, 64);
      s += __shfl_xor(s, 32, 64);
      if (lane < 16) xcpart[kh * 64 + nt * 16 + o15] = s;  // [2][64] view
    } else {
      // xc partials via MFMA (A=coef b128, B=x^T register fragments)
      f32x4 d = {0.f, 0.f, 0.f, 0.f};
#pragma unroll
      for (int ks = 0; ks < 8; ++ks) {
        int p = kh * 32 + ks * 4 + g;
        half8 a = *reinterpret_cast<const half8*>(cf_b + oc * 1024 + ((p ^ oc) << 4));
        d = __builtin_amdgcn_mfma_f32_16x16x32_f16(a, bfrag[ks].v, d, 0, 0, 0);
      }
      if (lane < 32) {  // D rows 0-7 (valid o) live in lanes 0-31
#pragma unroll
        for (int r = 0; r < 4; ++r)
          xcpart[kh * 512 + (g * 4 + r) * 64 + nt * 16 + o15] = d[r];
      }
    }
    __syncthreads();

    // ---- finalize: xc = partials/denom; wn = (G@xc)/||out|| ----
    {
      float xcv;
      if (pass == 0) {
        xcv = (xcpart[lane] + xcpart[64 + lane]) * (1.0f / 512.0f);
      } else {
        float se = 0.f;
#pragma unroll
        for (int g8 = 0; g8 < 8; ++g8) se += se_part[g8 * 8 + w];
        xcv = (xcpart[w * 64 + lane] + xcpart[512 + w * 64 + lane]) / se;
      }
      xc_s[(w << 6) + lane] = xcv;
      if (pass < 3) {
        const float4* xc4 = reinterpret_cast<const float4*>(&xc_s[w << 6]);
        float u0 = 0.f, u1 = 0.f, u2 = 0.f, u3 = 0.f;
#pragma unroll
        for (int k = 0; k < 16; ++k) {
          float4 xv = xc4[k];
          float2 ga = __half22float2(gh[2 * k]);
          float2 gb = __half22float2(gh[2 * k + 1]);
          u0 += ga.x * xv.x;
          u1 += ga.y * xv.y;
          u2 += gb.x * xv.z;
          u3 += gb.y * xv.w;
        }
        float uv = (u0 + u1) + (u2 + u3);
        float sq = uv * xcv;
#pragma unroll
        for (int m = 32; m; m >>= 1) sq += __shfl_xor(sq, m, 64);
        float wnv = uv / fmaxf(sqrtf(fmaxf(sq, 0.f)), 1e-12f);
        union { _Float16 hf; unsigned short us; } wc;
        wc.hf = (_Float16)wnv;
        *reinterpret_cast<unsigned short*>(
            wn_b + w * 128 + (((lane >> 3) ^ w) << 4) + ((lane & 7) << 1)) = wc.us;
      }
    }
    __syncthreads();
  }

  // ---- epilogue: out[b, obase+w, j=lane] = sum_l W[o][j][l] * xc[o][l] ----
  {
    const float* Wp = wg + ((((obase + w) << 6) + lane) << 6);
    float a0 = 0.f, a1 = 0.f, a2 = 0.f, a3 = 0.f;
#pragma unroll
    for (int k = 0; k < 16; ++k) {
      float4 wv = *reinterpret_cast<const float4*>(&Wp[k << 2]);
      float4 xv = *reinterpret_cast<const float4*>(&xc_s[(w << 6) + (k << 2)]);
      a0 += wv.x * xv.x; a1 += wv.y * xv.y;
      a2 += wv.z * xv.z; a3 += wv.w * xv.w;
    }
    outg[((b << 7) + obase + w) * 64 + lane] = (a0 + a1) + (a2 + a3);
  }
}

extern "C" void kernel_launch(void* const* d_in, const int* in_sizes, int n_in,
                              void* d_out, int out_size, void* d_ws, size_t ws_size,
                              hipStream_t stream) {
  const float* x = (const float*)d_in[0];     // (32, 512, 64) fp32
  const float* wgt = (const float*)d_in[1];   // (128, 64, 64) fp32
  float* out = (float*)d_out;                 // (32, 128, 64) fp32
  __half2* Gh2 = (__half2*)d_ws;              // 128*32*64 __half2 = 1 MB

  caps_gram<<<dim3(CO), dim3(256), 0, stream>>>(wgt, Gh2);
  caps_main<<<dim3(CO / OPB, CB), dim3(NT), 0, stream>>>(x, wgt, Gh2, out);
}

// Round 8
// 45.636 us; speedup vs baseline: 1.4441x; 1.3927x over previous
//
#include <hip/hip_runtime.h>
#include <hip/hip_fp16.h>

// CapsuleLinear, B=32, I=512, L=64, O=128, J=64, 3 routing iterations.
// Algebraic fusion (no priors):  out = W_o @ xc,  wn = (G_o @ xc)/||out||,
// G_o = W_o^T W_o (precomputed fp16-packed, 1 MB in d_ws).
// MFMA on v_mfma_f32_16x16x32_f16:
//  phase A: logits[i][o] = sum_l x[i][l] wn[o][l]   (A,B frags: b128 LDS reads)
//  phase B: xc[o][l]     = sum_i coef[o][i] x[i][l] (A: b128 LDS; B: x^T frags
//           gathered from LDS once, kept in 8 NAMED half8 registers)
// r6/r7 post-mortem: persistent arrays spilled to scratch (WRITE_SIZE 80 MB,
// VGPR_Count pinned at 64). Fixes:
//  - __launch_bounds__(NT, 2): r1-proven to unlock a 128+ VGPR allocation
//  - no G registers: fp16 G read from global in finalize (L2-resident, x32
//    block reuse; r7 proved fp16-G is precision-free)
//  - bfrag as 8 named half8 vars from named scalars (SROA-proof, no union)

#define CB 32
#define CI 512
#define CL 64
#define CO 128
#define OPB 8
#define NT 512

typedef _Float16 half8 __attribute__((ext_vector_type(8)));
typedef float f32x4 __attribute__((ext_vector_type(4)));

// Gh2[o][p][l] = (G[o][2p][l], G[o][2p+1][l]) as __half2; 128*32*64 elements.
__global__ __launch_bounds__(256) void caps_gram(const float* __restrict__ wg,
                                                 __half2* __restrict__ Gh2) {
  const int o = blockIdx.x;
  const int t = threadIdx.x;
  __shared__ float wl[64 * 65];  // W[o] padded
  __shared__ float gl[64 * 65];  // G[o] padded
#pragma unroll
  for (int k = 0; k < 16; ++k) {
    int f = t + 256 * k;
    int j = f >> 6, l = f & 63;
    wl[j * 65 + l] = wg[(o << 12) + f];
  }
  __syncthreads();
  const int l1 = t >> 2;
  const int l2b = (t & 3) << 4;
  float acc[16];
#pragma unroll
  for (int m = 0; m < 16; ++m) acc[m] = 0.f;
#pragma unroll 4
  for (int j = 0; j < 64; ++j) {
    float wa = wl[j * 65 + l1];
#pragma unroll
    for (int m = 0; m < 16; ++m) acc[m] += wa * wl[j * 65 + l2b + m];
  }
#pragma unroll
  for (int m = 0; m < 16; ++m) gl[l1 * 65 + l2b + m] = acc[m];
  __syncthreads();
#pragma unroll
  for (int k = 0; k < 8; ++k) {
    int e = t + 256 * k;          // 0..2047
    int l2p = e >> 6, l = e & 63;
    Gh2[(o << 11) + e] =
        __floats2half2_rn(gl[(2 * l2p) * 65 + l], gl[(2 * l2p + 1) * 65 + l]);
  }
}

__global__ __launch_bounds__(NT, 2) void caps_main(const float* __restrict__ xg,
                                                   const float* __restrict__ wg,
                                                   const __half2* __restrict__ Gh2,
                                                   float* __restrict__ outg) {
  const int b = blockIdx.y;
  const int obase = blockIdx.x * OPB;
  const int t = threadIdx.x;
  const int w = t >> 6;          // wave id
  const int lane = t & 63;
  const int g = lane >> 4;       // 16-lane group
  const int o15 = lane & 15;     // MFMA row/col index
  const int oc = o15 & 7;

  // xs: 32 i-subtiles x 4 l-subtiles, each 16x16 halves row-major = 512 B.
  __shared__ __align__(16) _Float16 xs[CI * CL];        // 65536 B
  __shared__ __align__(16) _Float16 coefT[OPB * CI];    // 8192 B (unit-XOR swz)
  __shared__ __align__(16) _Float16 wn16[OPB * CL];     // 1024 B (unit-XOR swz)
  __shared__ __align__(16) float xc_s[OPB * CL];        // 2048 B
  __shared__ __align__(16) float xcpart[2 * OPB * CL];  // 4096 B (dedicated)
  __shared__ float se_part[OPB * OPB];                  // 256 B
  char* const xs_b = reinterpret_cast<char*>(xs);
  char* const cf_b = reinterpret_cast<char*>(coefT);
  char* const wn_b = reinterpret_cast<char*>(wn16);
  // total 81152 B -> 2 blocks/CU (<= 81920)

  const int kh = w >> 2, nt = w & 3;  // phase-B: K-half, l-subtile

  // ---- stage x[b] -> fp16 subtiled LDS; coalesced float4 global reads ----
  {
    const float4* xg4 = reinterpret_cast<const float4*>(xg + b * (CI * CL));
#pragma unroll
    for (int k = 0; k < 8; ++k) {
      int f = t + NT * k;        // 8-half unit id: row i, l-unit lu
      int i = f >> 3, lu = f & 7;
      float4 a = xg4[2 * f];
      float4 c = xg4[2 * f + 1];
      union { _Float16 h[8]; uint4 u; } cv;
      cv.h[0] = (_Float16)a.x; cv.h[1] = (_Float16)a.y;
      cv.h[2] = (_Float16)a.z; cv.h[3] = (_Float16)a.w;
      cv.h[4] = (_Float16)c.x; cv.h[5] = (_Float16)c.y;
      cv.h[6] = (_Float16)c.z; cv.h[7] = (_Float16)c.w;
      int off = ((i >> 4) * 4 + (lu >> 1)) * 512 + (i & 15) * 32 + (lu & 1) * 16;
      *reinterpret_cast<uint4*>(xs_b + off) = cv.u;
    }
  }
  __syncthreads();

  // ---- x^T B-fragments: gathered from LDS ONCE into 8 named half8 regs ----
  // bfK[j] = x[kh*256 + K*32 + 8g + j][nt*16 + o15]
  half8 bf0, bf1, bf2, bf3, bf4, bf5, bf6, bf7;
  {
    const _Float16* xrd = reinterpret_cast<const _Float16*>(
        xs_b + ((kh * 16 + (g >> 1)) * 4 + nt) * 512 + ((lane & 16) << 4) +
        (o15 << 1));  // (g&1)*256 == (lane&16)<<4
#define GATHER(K)                                                         \
  {                                                                       \
    const _Float16* xk = xrd + (K)*2048; /* +K*4096 B */                  \
    _Float16 h0 = xk[0], h1 = xk[16], h2 = xk[32], h3 = xk[48];           \
    _Float16 h4 = xk[64], h5 = xk[80], h6 = xk[96], h7 = xk[112];         \
    bf##K = (half8){h0, h1, h2, h3, h4, h5, h6, h7};                      \
  }
    GATHER(0) GATHER(1) GATHER(2) GATHER(3)
    GATHER(4) GATHER(5) GATHER(6) GATHER(7)
#undef GATHER
  }

  for (int pass = 0; pass < 4; ++pass) {
    if (pass > 0) {
      // ---- phase A: logits via MFMA; exp; coef+se ----
      half8 bw0 = *reinterpret_cast<const half8*>(wn_b + oc * 128 + ((g ^ oc) << 4));
      half8 bw1 = *reinterpret_cast<const half8*>(wn_b + oc * 128 + (((4 + g) ^ oc) << 4));
      float sacc = 0.f;
#pragma unroll
      for (int ti = 0; ti < 4; ++ti) {
        const int itb = (16 * w + 4 * ti) * 512;  // i-subtile (4w+ti) byte base
        half8 a0 = *reinterpret_cast<const half8*>(
            xs_b + itb + ((g >> 1) * 512) + o15 * 32 + ((g & 1) << 4));
        half8 a1 = *reinterpret_cast<const half8*>(
            xs_b + itb + ((2 + (g >> 1)) * 512) + o15 * 32 + ((g & 1) << 4));
        f32x4 d = {0.f, 0.f, 0.f, 0.f};
        d = __builtin_amdgcn_mfma_f32_16x16x32_f16(a0, bw0, d, 0, 0, 0);
        d = __builtin_amdgcn_mfma_f32_16x16x32_f16(a1, bw1, d, 0, 0, 0);
        // |logits| <= ||x_i||*sigma_max(W_o) ~ 2.5: no max-subtraction needed
        float e0 = __expf(d[0]), e1 = __expf(d[1]);
        float e2 = __expf(d[2]), e3 = __expf(d[3]);
        sacc += (e0 + e1) + (e2 + e3);
        if (o15 < 8) {  // valid capsule columns only
          int p = 8 * w + 2 * ti + (g >> 1);          // 8-half unit index (i>>3)
          int base = o15 * 1024 + ((p ^ o15) << 4) + ((g & 1) << 3);
          union { _Float16 h[2]; uint u; } p0, p1;
          p0.h[0] = (_Float16)e0; p0.h[1] = (_Float16)e1;
          p1.h[0] = (_Float16)e2; p1.h[1] = (_Float16)e3;
          *reinterpret_cast<uint*>(cf_b + base) = p0.u;
          *reinterpret_cast<uint*>(cf_b + base + 4) = p1.u;
        }
      }
      sacc += __shfl_xor(sacc, 16, 64);
      sacc += __shfl_xor(sacc, 32, 64);
      if (lane < 8) se_part[w * 8 + lane] = sacc;
      __syncthreads();
    }

    // ---- phase B ----
    if (pass == 0) {
      // xbar partials straight from register fragments
      float s = 0.f;
#define SUMF(K)                                                           \
  {                                                                       \
    s += (float)bf##K[0] + (float)bf##K[1] + (float)bf##K[2] +            \
         (float)bf##K[3] + (float)bf##K[4] + (float)bf##K[5] +            \
         (float)bf##K[6] + (float)bf##K[7];                               \
  }
      SUMF(0) SUMF(1) SUMF(2) SUMF(3) SUMF(4) SUMF(5) SUMF(6) SUMF(7)
#undef SUMF
      s += __shfl_xor(s, 16, 64);
      s += __shfl_xor(s, 32, 64);
      if (lane < 16) xcpart[kh * 64 + nt * 16 + o15] = s;  // [2][64] view
    } else {
      // xc partials via MFMA (A=coef b128, B=x^T register fragments)
      f32x4 d = {0.f, 0.f, 0.f, 0.f};
#define MFMAK(K)                                                          \
  {                                                                       \
    int p = kh * 32 + (K)*4 + g;                                          \
    half8 a = *reinterpret_cast<const half8*>(cf_b + oc * 1024 +          \
                                              ((p ^ oc) << 4));           \
    d = __builtin_amdgcn_mfma_f32_16x16x32_f16(a, bf##K, d, 0, 0, 0);     \
  }
      MFMAK(0) MFMAK(1) MFMAK(2) MFMAK(3)
      MFMAK(4) MFMAK(5) MFMAK(6) MFMAK(7)
#undef MFMAK
      if (lane < 32) {  // D rows 0-7 (valid o) live in lanes 0-31
#pragma unroll
        for (int r = 0; r < 4; ++r)
          xcpart[kh * 512 + (g * 4 + r) * 64 + nt * 16 + o15] = d[r];
      }
    }
    __syncthreads();

    // ---- finalize: xc = partials/denom; wn = (G@xc)/||out|| ----
    {
      float xcv;
      if (pass == 0) {
        xcv = (xcpart[lane] + xcpart[64 + lane]) * (1.0f / 512.0f);
      } else {
        float se = 0.f;
#pragma unroll
        for (int g8 = 0; g8 < 8; ++g8) se += se_part[g8 * 8 + w];
        xcv = (xcpart[w * 64 + lane] + xcpart[512 + w * 64 + lane]) / se;
      }
      xc_s[(w << 6) + lane] = xcv;
      if (pass < 3) {
        // u = G @ xc with fp16 G streamed from global (L2-resident, no regs)
        const __half2* Gp = Gh2 + ((obase + w) << 11) + lane;
        const float4* xc4 = reinterpret_cast<const float4*>(&xc_s[w << 6]);
        float u0 = 0.f, u1 = 0.f, u2 = 0.f, u3 = 0.f;
#pragma unroll
        for (int k = 0; k < 16; ++k) {
          float4 xv = xc4[k];
          float2 ga = __half22float2(Gp[(2 * k) << 6]);
          float2 gb = __half22float2(Gp[(2 * k + 1) << 6]);
          u0 += ga.x * xv.x;
          u1 += ga.y * xv.y;
          u2 += gb.x * xv.z;
          u3 += gb.y * xv.w;
        }
        float uv = (u0 + u1) + (u2 + u3);
        float sq = uv * xcv;
#pragma unroll
        for (int m = 32; m; m >>= 1) sq += __shfl_xor(sq, m, 64);
        float wnv = uv / fmaxf(sqrtf(fmaxf(sq, 0.f)), 1e-12f);
        union { _Float16 hf; unsigned short us; } wc;
        wc.hf = (_Float16)wnv;
        *reinterpret_cast<unsigned short*>(
            wn_b + w * 128 + (((lane >> 3) ^ w) << 4) + ((lane & 7) << 1)) = wc.us;
      }
    }
    __syncthreads();
  }

  // ---- epilogue: out[b, obase+w, j=lane] = sum_l W[o][j][l] * xc[o][l] ----
  {
    const float* Wp = wg + ((((obase + w) << 6) + lane) << 6);
    float a0 = 0.f, a1 = 0.f, a2 = 0.f, a3 = 0.f;
#pragma unroll
    for (int k = 0; k < 16; ++k) {
      float4 wv = *reinterpret_cast<const float4*>(&Wp[k << 2]);
      float4 xv = *reinterpret_cast<const float4*>(&xc_s[(w << 6) + (k << 2)]);
      a0 += wv.x * xv.x; a1 += wv.y * xv.y;
      a2 += wv.z * xv.z; a3 += wv.w * xv.w;
    }
    outg[((b << 7) + obase + w) * 64 + lane] = (a0 + a1) + (a2 + a3);
  }
}

extern "C" void kernel_launch(void* const* d_in, const int* in_sizes, int n_in,
                              void* d_out, int out_size, void* d_ws, size_t ws_size,
                              hipStream_t stream) {
  const float* x = (const float*)d_in[0];     // (32, 512, 64) fp32
  const float* wgt = (const float*)d_in[1];   // (128, 64, 64) fp32
  float* out = (float*)d_out;                 // (32, 128, 64) fp32
  __half2* Gh2 = (__half2*)d_ws;              // 128*32*64 __half2 = 1 MB

  caps_gram<<<dim3(CO), dim3(256), 0, stream>>>(wgt, Gh2);
  caps_main<<<dim3(CO / OPB, CB), dim3(NT), 0, stream>>>(x, wgt, Gh2, out);
}

// Round 9
// 42.797 us; speedup vs baseline: 1.5399x; 1.0663x over previous
//
#include <hip/hip_runtime.h>
#include <hip/hip_fp16.h>

// CapsuleLinear, B=32, I=512, L=64, O=128, J=64, 3 routing iterations.
// Algebraic fusion (no priors):  out = W_o @ xc,  wn = (G_o @ xc)/||out||,
// G_o = W_o^T W_o (precomputed fp16-packed, lane-major, 1 MB in d_ws).
// MFMA on v_mfma_f32_16x16x32_f16:
//  phase A: logits[i][o] = sum_l x[i][l] wn[o][l]   (b128 LDS reads, at the
//           wave64 bank floor already)
//  phase B: xc[o][l]     = sum_i coef[o][i] x[i][l] (A: b128; B: x^T fragments
//           in 8 named half8 regs, gathered once via paired-dword broadcast)
// r8 post-mortem: per-pass G-streaming put 32 L2-latency loads on the
// critical path each pass. Here G lives in 8 named uint4 regs (fp16 pairs),
// loaded once with fully-coalesced uint4 reads (lane-major Gq layout).
// Persistent regs = 64 (bf 32 + gq 32) -- r1-proven to fit a 128-VGPR
// allocation without spills under __launch_bounds__(NT, 2).

#define CB 32
#define CI 512
#define CL 64
#define CO 128
#define OPB 8
#define NT 512

typedef _Float16 half8 __attribute__((ext_vector_type(8)));
typedef float f32x4 __attribute__((ext_vector_type(4)));

static __device__ __forceinline__ _Float16 half_sel(uint v, int sh) {
  union { unsigned short s; _Float16 h; } c;
  c.s = (unsigned short)(v >> sh);
  return c.h;
}

// Gq layout (as __half2 array): idx = ((o*8 + k)*64 + lane)*4 + q
// holds pair p = 4k+q for column `lane`:  (G[o][8k+2q][lane], G[o][8k+2q+1][lane])
// -> per (o,k): 64 lanes x 16 B contiguous = one coalesced uint4 per lane.
__global__ __launch_bounds__(256) void caps_gram(const float* __restrict__ wg,
                                                 __half2* __restrict__ Gq) {
  const int o = blockIdx.x;
  const int t = threadIdx.x;
  __shared__ float wl[64 * 65];  // W[o] padded
  __shared__ float gl[64 * 65];  // G[o] padded
#pragma unroll
  for (int k = 0; k < 16; ++k) {
    int f = t + 256 * k;
    int j = f >> 6, l = f & 63;
    wl[j * 65 + l] = wg[(o << 12) + f];
  }
  __syncthreads();
  const int l1 = t >> 2;
  const int l2b = (t & 3) << 4;
  float acc[16];
#pragma unroll
  for (int m = 0; m < 16; ++m) acc[m] = 0.f;
#pragma unroll 4
  for (int j = 0; j < 64; ++j) {
    float wa = wl[j * 65 + l1];
#pragma unroll
    for (int m = 0; m < 16; ++m) acc[m] += wa * wl[j * 65 + l2b + m];
  }
#pragma unroll
  for (int m = 0; m < 16; ++m) gl[l1 * 65 + l2b + m] = acc[m];
  __syncthreads();
#pragma unroll
  for (int j = 0; j < 8; ++j) {
    int e = t + 256 * j;             // 0..2047
    int k = e >> 8;                  // 0..7
    int l = (e >> 2) & 63;
    int q = e & 3;
    int l2 = 8 * k + 2 * q;
    Gq[(o << 11) + e] = __floats2half2_rn(gl[l2 * 65 + l], gl[(l2 + 1) * 65 + l]);
  }
}

__global__ __launch_bounds__(NT, 2) void caps_main(const float* __restrict__ xg,
                                                   const float* __restrict__ wg,
                                                   const __half2* __restrict__ Gq,
                                                   float* __restrict__ outg) {
  const int b = blockIdx.y;
  const int obase = blockIdx.x * OPB;
  const int t = threadIdx.x;
  const int w = t >> 6;          // wave id
  const int lane = t & 63;
  const int g = lane >> 4;       // 16-lane group
  const int o15 = lane & 15;     // MFMA row/col index
  const int oc = o15 & 7;

  // xs: 32 i-subtiles x 4 l-subtiles, each 16x16 halves row-major = 512 B.
  __shared__ __align__(16) _Float16 xs[CI * CL];        // 65536 B
  __shared__ __align__(16) _Float16 coefT[OPB * CI];    // 8192 B (unit-XOR swz)
  __shared__ __align__(16) _Float16 wn16[OPB * CL];     // 1024 B (unit-XOR swz)
  __shared__ __align__(16) float xc_s[OPB * CL];        // 2048 B
  __shared__ __align__(16) float xcpart[2 * OPB * CL];  // 4096 B (dedicated)
  __shared__ float se_part[OPB * OPB];                  // 256 B
  char* const xs_b = reinterpret_cast<char*>(xs);
  char* const cf_b = reinterpret_cast<char*>(coefT);
  char* const wn_b = reinterpret_cast<char*>(wn16);
  // total 81152 B -> 2 blocks/CU (<= 81920)

  const int kh = w >> 2, nt = w & 3;  // phase-B: K-half, l-subtile

  // ---- G column in 8 named uint4 (fp16 pairs), coalesced one-time load ----
  uint4 gq0, gq1, gq2, gq3, gq4, gq5, gq6, gq7;
  {
    const uint4* Gp = reinterpret_cast<const uint4*>(Gq) +
                      (((obase + w) << 3) << 6) + lane;
    gq0 = Gp[0 * 64]; gq1 = Gp[1 * 64]; gq2 = Gp[2 * 64]; gq3 = Gp[3 * 64];
    gq4 = Gp[4 * 64]; gq5 = Gp[5 * 64]; gq6 = Gp[6 * 64]; gq7 = Gp[7 * 64];
  }

  // ---- stage x[b] -> fp16 subtiled LDS; coalesced float4 global reads ----
  {
    const float4* xg4 = reinterpret_cast<const float4*>(xg + b * (CI * CL));
#pragma unroll
    for (int k = 0; k < 8; ++k) {
      int f = t + NT * k;        // 8-half unit id: row i, l-unit lu
      int i = f >> 3, lu = f & 7;
      float4 a = xg4[2 * f];
      float4 c = xg4[2 * f + 1];
      union { _Float16 h[8]; uint4 u; } cv;
      cv.h[0] = (_Float16)a.x; cv.h[1] = (_Float16)a.y;
      cv.h[2] = (_Float16)a.z; cv.h[3] = (_Float16)a.w;
      cv.h[4] = (_Float16)c.x; cv.h[5] = (_Float16)c.y;
      cv.h[6] = (_Float16)c.z; cv.h[7] = (_Float16)c.w;
      int off = ((i >> 4) * 4 + (lu >> 1)) * 512 + (i & 15) * 32 + (lu & 1) * 16;
      *reinterpret_cast<uint4*>(xs_b + off) = cv.u;
    }
  }
  __syncthreads();

  // ---- x^T B-fragments: gathered ONCE into 8 named half8 regs ----
  // bfK[j] = x[kh*256 + K*32 + 8g + j][nt*16 + o15].
  // Paired-dword trick: lanes o15=2m,2m+1 read the same dword (broadcast),
  // each extracts its half -> conflicts drop from 8-way to ~4-way.
  half8 bf0, bf1, bf2, bf3, bf4, bf5, bf6, bf7;
  {
    const uint* xrd32 = reinterpret_cast<const uint*>(
                            xs_b + ((kh * 16 + (g >> 1)) * 4 + nt) * 512 +
                            ((lane & 16) << 4)) +
                        (o15 >> 1);
    const int sh = (o15 & 1) << 4;
#define GATHER(K)                                                         \
  {                                                                       \
    const uint* xk = xrd32 + (K)*1024; /* +K*4096 B */                    \
    uint q0 = xk[0], q1 = xk[8], q2 = xk[16], q3 = xk[24];                \
    uint q4 = xk[32], q5 = xk[40], q6 = xk[48], q7 = xk[56];              \
    bf##K = (half8){half_sel(q0, sh), half_sel(q1, sh), half_sel(q2, sh), \
                    half_sel(q3, sh), half_sel(q4, sh), half_sel(q5, sh), \
                    half_sel(q6, sh), half_sel(q7, sh)};                  \
  }
    GATHER(0) GATHER(1) GATHER(2) GATHER(3)
    GATHER(4) GATHER(5) GATHER(6) GATHER(7)
#undef GATHER
  }

  for (int pass = 0; pass < 4; ++pass) {
    if (pass > 0) {
      // ---- phase A: logits via MFMA; exp; coef+se ----
      half8 bw0 = *reinterpret_cast<const half8*>(wn_b + oc * 128 + ((g ^ oc) << 4));
      half8 bw1 = *reinterpret_cast<const half8*>(wn_b + oc * 128 + (((4 + g) ^ oc) << 4));
      float sacc = 0.f;
#pragma unroll
      for (int ti = 0; ti < 4; ++ti) {
        const int itb = (16 * w + 4 * ti) * 512;  // i-subtile (4w+ti) byte base
        half8 a0 = *reinterpret_cast<const half8*>(
            xs_b + itb + ((g >> 1) * 512) + o15 * 32 + ((g & 1) << 4));
        half8 a1 = *reinterpret_cast<const half8*>(
            xs_b + itb + ((2 + (g >> 1)) * 512) + o15 * 32 + ((g & 1) << 4));
        f32x4 d = {0.f, 0.f, 0.f, 0.f};
        d = __builtin_amdgcn_mfma_f32_16x16x32_f16(a0, bw0, d, 0, 0, 0);
        d = __builtin_amdgcn_mfma_f32_16x16x32_f16(a1, bw1, d, 0, 0, 0);
        // |logits| <= ||x_i||*sigma_max(W_o) ~ 2.5: no max-subtraction needed
        float e0 = __expf(d[0]), e1 = __expf(d[1]);
        float e2 = __expf(d[2]), e3 = __expf(d[3]);
        sacc += (e0 + e1) + (e2 + e3);
        if (o15 < 8) {  // valid capsule columns only
          int p = 8 * w + 2 * ti + (g >> 1);          // 8-half unit index (i>>3)
          int base = o15 * 1024 + ((p ^ o15) << 4) + ((g & 1) << 3);
          union { _Float16 h[2]; uint u; } p0, p1;
          p0.h[0] = (_Float16)e0; p0.h[1] = (_Float16)e1;
          p1.h[0] = (_Float16)e2; p1.h[1] = (_Float16)e3;
          *reinterpret_cast<uint*>(cf_b + base) = p0.u;
          *reinterpret_cast<uint*>(cf_b + base + 4) = p1.u;
        }
      }
      sacc += __shfl_xor(sacc, 16, 64);
      sacc += __shfl_xor(sacc, 32, 64);
      if (lane < 8) se_part[w * 8 + lane] = sacc;
      __syncthreads();
    }

    // ---- phase B ----
    if (pass == 0) {
      // xbar partials straight from register fragments
      float s = 0.f;
#define SUMF(K)                                                           \
  {                                                                       \
    s += (float)bf##K[0] + (float)bf##K[1] + (float)bf##K[2] +            \
         (float)bf##K[3] + (float)bf##K[4] + (float)bf##K[5] +            \
         (float)bf##K[6] + (float)bf##K[7];                               \
  }
      SUMF(0) SUMF(1) SUMF(2) SUMF(3) SUMF(4) SUMF(5) SUMF(6) SUMF(7)
#undef SUMF
      s += __shfl_xor(s, 16, 64);
      s += __shfl_xor(s, 32, 64);
      if (lane < 16) xcpart[kh * 64 + nt * 16 + o15] = s;  // [2][64] view
    } else {
      // xc partials via MFMA (A=coef b128, B=x^T register fragments)
      f32x4 d = {0.f, 0.f, 0.f, 0.f};
#define MFMAK(K)                                                          \
  {                                                                       \
    int p = kh * 32 + (K)*4 + g;                                          \
    half8 a = *reinterpret_cast<const half8*>(cf_b + oc * 1024 +          \
                                              ((p ^ oc) << 4));           \
    d = __builtin_amdgcn_mfma_f32_16x16x32_f16(a, bf##K, d, 0, 0, 0);     \
  }
      MFMAK(0) MFMAK(1) MFMAK(2) MFMAK(3)
      MFMAK(4) MFMAK(5) MFMAK(6) MFMAK(7)
#undef MFMAK
      if (lane < 32) {  // D rows 0-7 (valid o) live in lanes 0-31
#pragma unroll
        for (int r = 0; r < 4; ++r)
          xcpart[kh * 512 + (g * 4 + r) * 64 + nt * 16 + o15] = d[r];
      }
    }
    __syncthreads();

    // ---- finalize: xc = partials/denom; wn = (G@xc)/||out|| ----
    {
      float xcv;
      if (pass == 0) {
        xcv = (xcpart[lane] + xcpart[64 + lane]) * (1.0f / 512.0f);
      } else {
        float se = 0.f;
#pragma unroll
        for (int g8 = 0; g8 < 8; ++g8) se += se_part[g8 * 8 + w];
        xcv = (xcpart[w * 64 + lane] + xcpart[512 + w * 64 + lane]) / se;
      }
      xc_s[(w << 6) + lane] = xcv;
      if (pass < 3) {
        // u = G @ xc entirely from registers (gq holds fp16 G pairs)
        const float4* xc4 = reinterpret_cast<const float4*>(&xc_s[w << 6]);
        float u0 = 0.f, u1 = 0.f, u2 = 0.f, u3 = 0.f;
#define GDOT(K)                                                           \
  {                                                                       \
    float4 xa = xc4[2 * (K)], xb = xc4[2 * (K) + 1];                      \
    float2 h0 = __half22float2(*reinterpret_cast<const __half2*>(&gq##K.x)); \
    float2 h1 = __half22float2(*reinterpret_cast<const __half2*>(&gq##K.y)); \
    float2 h2 = __half22float2(*reinterpret_cast<const __half2*>(&gq##K.z)); \
    float2 h3 = __half22float2(*reinterpret_cast<const __half2*>(&gq##K.w)); \
    u0 += h0.x * xa.x; u1 += h0.y * xa.y;                                 \
    u2 += h1.x * xa.z; u3 += h1.y * xa.w;                                 \
    u0 += h2.x * xb.x; u1 += h2.y * xb.y;                                 \
    u2 += h3.x * xb.z; u3 += h3.y * xb.w;                                 \
  }
        GDOT(0) GDOT(1) GDOT(2) GDOT(3) GDOT(4) GDOT(5) GDOT(6) GDOT(7)
#undef GDOT
        float uv = (u0 + u1) + (u2 + u3);
        float sq = uv * xcv;
#pragma unroll
        for (int m = 32; m; m >>= 1) sq += __shfl_xor(sq, m, 64);
        float wnv = uv / fmaxf(sqrtf(fmaxf(sq, 0.f)), 1e-12f);
        union { _Float16 hf; unsigned short us; } wc;
        wc.hf = (_Float16)wnv;
        *reinterpret_cast<unsigned short*>(
            wn_b + w * 128 + (((lane >> 3) ^ w) << 4) + ((lane & 7) << 1)) = wc.us;
      }
    }
    __syncthreads();
  }

  // ---- epilogue: out[b, obase+w, j=lane] = sum_l W[o][j][l] * xc[o][l] ----
  {
    const float* Wp = wg + ((((obase + w) << 6) + lane) << 6);
    float a0 = 0.f, a1 = 0.f, a2 = 0.f, a3 = 0.f;
#pragma unroll
    for (int k = 0; k < 16; ++k) {
      float4 wv = *reinterpret_cast<const float4*>(&Wp[k << 2]);
      float4 xv = *reinterpret_cast<const float4*>(&xc_s[(w << 6) + (k << 2)]);
      a0 += wv.x * xv.x; a1 += wv.y * xv.y;
      a2 += wv.z * xv.z; a3 += wv.w * xv.w;
    }
    outg[((b << 7) + obase + w) * 64 + lane] = (a0 + a1) + (a2 + a3);
  }
}

extern "C" void kernel_launch(void* const* d_in, const int* in_sizes, int n_in,
                              void* d_out, int out_size, void* d_ws, size_t ws_size,
                              hipStream_t stream) {
  const float* x = (const float*)d_in[0];     // (32, 512, 64) fp32
  const float* wgt = (const float*)d_in[1];   // (128, 64, 64) fp32
  float* out = (float*)d_out;                 // (32, 128, 64) fp32
  __half2* Gq = (__half2*)d_ws;               // 128*8*64*4 __half2 = 1 MB

  caps_gram<<<dim3(CO), dim3(256), 0, stream>>>(wgt, Gq);
  caps_main<<<dim3(CO / OPB, CB), dim3(NT), 0, stream>>>(x, wgt, Gq, out);
}